// Round 14
// baseline (153.848 us; speedup 1.0000x reference)
//
#include <hip/hip_runtime.h>
#include <hip/hip_bf16.h>

#define S_SRC 4096
#define DIM 128
#define BATCH 2
#define NSP 8
#define NQB 32    // 256-row q-blocks
#define NQG 512   // 16-row q-groups total
#define NWIN 8    // (S_SRC/NSP)/64 key windows per split

typedef unsigned short u16;
typedef unsigned int u32;
typedef __bf16 bf16x8 __attribute__((ext_vector_type(8)));
typedef float f32x4 __attribute__((ext_vector_type(4)));
typedef u32 u32x4 __attribute__((ext_vector_type(4)));
typedef u16 u16x8 __attribute__((ext_vector_type(8)));

__device__ __forceinline__ __bf16 bf_hi(float x) { return (__bf16)x; }
__device__ __forceinline__ __bf16 bf_lo(float x, __bf16 h) { return (__bf16)(x - (float)h); }
__device__ __forceinline__ u16 bfu(__bf16 h) { return __builtin_bit_cast(u16, h); }
__device__ __forceinline__ u16 f2bu(float x) { return __builtin_bit_cast(u16, (__bf16)x); }
__device__ __forceinline__ float bu2f(u16 u) { return (float)__builtin_bit_cast(__bf16, u); }
__device__ __forceinline__ u32 pk2(float lo, float hi) {
  return (u32)f2bu(lo) | ((u32)f2bu(hi) << 16);
}
// native exp2: v_exp_f32 IS 2^x on AMD — single TRANS instruction, no pre-multiply
__device__ __forceinline__ float ex2(float x) {
  float r;
  asm("v_exp_f32 %0, %1" : "=v"(r) : "v"(x));
  return r;
}
__device__ __forceinline__ void g2l16(const u16* src, u16* ldst) {
  __builtin_amdgcn_global_load_lds((const __attribute__((address_space(1))) void*)src,
                                   (__attribute__((address_space(3))) void*)ldst, 16, 0, 0);
}
#define MFMA __builtin_amdgcn_mfma_f32_16x16x32_bf16

// ---------------- kernel 0: transpose + hi/lo split the weight matrices ----------------
// Wq also folds log2(e)/sqrt(128) so all softmax exponentials run in base-2 (v_exp_f32).
__global__ __launch_bounds__(256) void k_wsplit(const float* __restrict__ wq,
                                                const float* __restrict__ wk,
                                                const float* __restrict__ wv,
                                                u16* __restrict__ wt) {
  int idx = blockIdx.x * 256 + threadIdx.x;  // 3*128*128 = 49152
  int mat = idx >> 14;
  int r = idx & 16383;
  int d = r >> 7, e = r & 127;
  const float* w = (mat == 0) ? wq : ((mat == 1) ? wk : wv);
  float x = w[r];
  if (mat == 0) x *= 0.12751744684693238f;  // log2(e) / sqrt(128)
  __bf16 h = bf_hi(x);
  __bf16 l = bf_lo(x, h);
  wt[((mat * 2 + 0) * 128 + e) * 128 + d] = bfu(h);
  wt[((mat * 2 + 1) * 128 + e) * 128 + d] = bfu(l);
}

// ---------------- kernel 1: QKV projection (fused 3 mats, X read once) ----------------
__global__ __launch_bounds__(256) void k_proj(const float* __restrict__ X,
                                              const u16* __restrict__ wt,
                                              u16* __restrict__ Qh, u16* __restrict__ Ql,
                                              u16* __restrict__ Kh, u16* __restrict__ Kl,
                                              u16* __restrict__ VT) {
  const int b = blockIdx.x >> 7;
  const int tile = blockIdx.x & 127;
  const int tid = threadIdx.x;
  const int w = tid >> 6, lane = tid & 63, g = lane >> 4, l16 = lane & 15;

  bf16x8 a_h[2][4], a_l[2][4];
#pragma unroll
  for (int mf = 0; mf < 2; ++mf) {
    int row = tile * 32 + mf * 16 + l16;
    const float* xr = X + ((size_t)b * S_SRC + row) * DIM;
#pragma unroll
    for (int kf = 0; kf < 4; ++kf) {
      int d0 = kf * 32 + g * 8;
      f32x4 x0 = *(const f32x4*)(xr + d0);
      f32x4 x1 = *(const f32x4*)(xr + d0 + 4);
#pragma unroll
      for (int j = 0; j < 4; ++j) {
        __bf16 h0 = bf_hi(x0[j]);
        __bf16 h1 = bf_hi(x1[j]);
        a_h[mf][kf][j] = h0;
        a_l[mf][kf][j] = bf_lo(x0[j], h0);
        a_h[mf][kf][4 + j] = h1;
        a_l[mf][kf][4 + j] = bf_lo(x1[j], h1);
      }
    }
  }

#pragma unroll
  for (int mat = 0; mat < 3; ++mat) {
    const u16* wth = wt + (mat * 2 + 0) * 16384;
    const u16* wtl = wt + (mat * 2 + 1) * 16384;
#pragma unroll
    for (int nf = 0; nf < 2; ++nf) {
      int col = w * 32 + nf * 16 + l16;
      f32x4 acc[2];
      acc[0] = (f32x4){0.f, 0.f, 0.f, 0.f};
      acc[1] = (f32x4){0.f, 0.f, 0.f, 0.f};
#pragma unroll
      for (int kf = 0; kf < 4; ++kf) {
        int d0 = kf * 32 + g * 8;
        bf16x8 bh = *(const bf16x8*)(const void*)(wth + col * 128 + d0);
        bf16x8 bl = *(const bf16x8*)(const void*)(wtl + col * 128 + d0);
#pragma unroll
        for (int mf = 0; mf < 2; ++mf) {
          acc[mf] = MFMA(a_h[mf][kf], bh, acc[mf], 0, 0, 0);
          acc[mf] = MFMA(a_h[mf][kf], bl, acc[mf], 0, 0, 0);
          acc[mf] = MFMA(a_l[mf][kf], bh, acc[mf], 0, 0, 0);
        }
      }
#pragma unroll
      for (int mf = 0; mf < 2; ++mf)
#pragma unroll
        for (int r = 0; r < 4; ++r) {
          int row = tile * 32 + mf * 16 + g * 4 + r;
          float v = acc[mf][r];
          if (mat == 2) {
            VT[((size_t)b * DIM + col) * S_SRC + row] = f2bu(v);
          } else {
            __bf16 h = bf_hi(v);
            __bf16 l = bf_lo(v, h);
            size_t o = ((size_t)b * S_SRC + row) * DIM + col;
            if (mat == 0) { Qh[o] = bfu(h); Ql[o] = bfu(l); }
            else          { Kh[o] = bfu(h); Kl[o] = bfu(l); }
          }
        }
    }
  }
}

// ---------------- kernel 2: flash attention + fused last-arriver combine ----------------
// Swapped QK^T (A=K, B=Q). Per wave: 2 q-groups of 16 rows. 8 windows of 64 keys.
// Scores in log2 domain (log2e folded into Wq); exponentials are v_exp_f32.
// After partials: 8th-arriving block per qb combines the 8 KV-split partials -> out.
__global__ __launch_bounds__(512, 2) void k_attn(const u16* __restrict__ Qh, const u16* __restrict__ Ql,
                                                 const u16* __restrict__ Kh, const u16* __restrict__ Kl,
                                                 const u16* __restrict__ VT,
                                                 float* __restrict__ Pm, float* __restrict__ Pl,
                                                 u16* __restrict__ PO, int* __restrict__ cnt,
                                                 float* __restrict__ out) {
  const int bid = blockIdx.x;
  const int sp = bid & 7;     // kv split 0..7 (== XCD id)
  const int qb = bid >> 3;    // 256-row q-block 0..31
  const int b = qb >> 4;
  const int tid = threadIdx.x;
  const int w = tid >> 6, lane = tid & 63, g = lane >> 4, l16 = lane & 15;

  __shared__ alignas(16) u16 kbuf[3][16384];  // 96KB: [hi 64x128 | lo 64x128] chunk-swizzled
  __shared__ alignas(16) u16 vbuf[3][8192];   // 48KB: [128d x 64s] chunk-swizzled
  __shared__ float scl[NSP][256];             // 8KB: combine scale table
  __shared__ int ticket;

  // ---- Q fragments (hi/lo), 32 q-rows: 2 groups of 16 ----
  const int gr0 = qb * 256 + w * 32;
  bf16x8 qh0[4], ql0[4], qh1[4], ql1[4];
  {
    const u16* p0h = Qh + ((size_t)gr0 + l16) * DIM;
    const u16* p0l = Ql + ((size_t)gr0 + l16) * DIM;
    const u16* p1h = Qh + ((size_t)gr0 + 16 + l16) * DIM;
    const u16* p1l = Ql + ((size_t)gr0 + 16 + l16) * DIM;
#pragma unroll
    for (int kf = 0; kf < 4; ++kf) {
      int d0 = kf * 32 + g * 8;
      qh0[kf] = *(const bf16x8*)(const void*)(p0h + d0);
      ql0[kf] = *(const bf16x8*)(const void*)(p0l + d0);
      qh1[kf] = *(const bf16x8*)(const void*)(p1h + d0);
      ql1[kf] = *(const bf16x8*)(const void*)(p1l + d0);
    }
  }

  f32x4 acc0[8], acc1[8];
#pragma unroll
  for (int nf = 0; nf < 8; ++nf) {
    acc0[nf] = (f32x4){0.f, 0.f, 0.f, 0.f};
    acc1[nf] = (f32x4){0.f, 0.f, 0.f, 0.f};
  }
  float m0 = -1e30f, m1 = -1e30f, l0 = 0.f, l1 = 0.f;

  const int key_base = sp * (S_SRC / NSP);
  const u16* KhB = Kh + (size_t)b * S_SRC * DIM;
  const u16* KlB = Kl + (size_t)b * S_SRC * DIM;
  const u16* VTB = VT + (size_t)b * DIM * S_SRC;

  // staging (512 threads x 6 chunks of 16B), chunk-XOR swizzle
  const int kkey0 = tid >> 4;                           // key row 0..31 (pass0); +32 pass1
  const int kks = ((tid & 15) ^ (kkey0 & 15)) << 3;     // swizzled source d-offset (elems)
  const int vd0 = tid >> 3;                             // V d-row 0..63 (pass0); +64 pass1
  const int vks = ((tid & 7) ^ ((vd0 >> 1) & 7)) << 3;  // swizzled source s-offset (elems)
  const int wb = w * 512;                               // wave-uniform LDS chunk base (u16)
  const int mg = ((g & 1) << 1) | (g >> 1);             // V key-chunk permutation {0,2,1,3}

#define STAGE(BUF, KEY0)                                                             \
  {                                                                                  \
    g2l16(KhB + ((size_t)((KEY0) + kkey0)) * DIM + kks,      &kbuf[BUF][wb]);        \
    g2l16(KhB + ((size_t)((KEY0) + 32 + kkey0)) * DIM + kks, &kbuf[BUF][4096 + wb]); \
    g2l16(KlB + ((size_t)((KEY0) + kkey0)) * DIM + kks,      &kbuf[BUF][8192 + wb]); \
    g2l16(KlB + ((size_t)((KEY0) + 32 + kkey0)) * DIM + kks, &kbuf[BUF][12288 + wb]);\
    g2l16(VTB + (size_t)vd0 * S_SRC + (KEY0) + vks,          &vbuf[BUF][wb]);        \
    g2l16(VTB + (size_t)(64 + vd0) * S_SRC + (KEY0) + vks,   &vbuf[BUF][4096 + wb]); \
  }

#define SMPACK(S, MR, LR, ACC, PA, PB)                                               \
  {                                                                                  \
    float mxa = fmaxf(fmaxf(fmaxf(S[0][0], S[0][1]), fmaxf(S[0][2], S[0][3])),       \
                      fmaxf(fmaxf(S[1][0], S[1][1]), fmaxf(S[1][2], S[1][3])));      \
    float mxb = fmaxf(fmaxf(fmaxf(S[2][0], S[2][1]), fmaxf(S[2][2], S[2][3])),       \
                      fmaxf(fmaxf(S[3][0], S[3][1]), fmaxf(S[3][2], S[3][3])));      \
    float mx = fmaxf(mxa, mxb);                                                      \
    mx = fmaxf(mx, __shfl_xor(mx, 16, 64));                                          \
    mx = fmaxf(mx, __shfl_xor(mx, 32, 64));                                          \
    if (!__all(mx - MR <= 11.5f)) {                                                  \
      float mn = fmaxf(MR, mx);                                                      \
      float f = ex2(MR - mn);                                                        \
      LR *= f; MR = mn;                                                              \
      float fr0 = __shfl(f, g * 4 + 0, 64);                                          \
      float fr1 = __shfl(f, g * 4 + 1, 64);                                          \
      float fr2 = __shfl(f, g * 4 + 2, 64);                                          \
      float fr3 = __shfl(f, g * 4 + 3, 64);                                          \
      _Pragma("unroll")                                                              \
      for (int nf = 0; nf < 8; ++nf) {                                               \
        ACC[nf][0] *= fr0; ACC[nf][1] *= fr1;                                        \
        ACC[nf][2] *= fr2; ACC[nf][3] *= fr3;                                        \
      }                                                                              \
    }                                                                                \
    float e0 = ex2(S[0][0] - MR), e1 = ex2(S[0][1] - MR);                            \
    float e2 = ex2(S[0][2] - MR), e3 = ex2(S[0][3] - MR);                            \
    float e4 = ex2(S[1][0] - MR), e5 = ex2(S[1][1] - MR);                            \
    float e6 = ex2(S[1][2] - MR), e7 = ex2(S[1][3] - MR);                            \
    float f0 = ex2(S[2][0] - MR), f1 = ex2(S[2][1] - MR);                            \
    float f2 = ex2(S[2][2] - MR), f3 = ex2(S[2][3] - MR);                            \
    float f4 = ex2(S[3][0] - MR), f5 = ex2(S[3][1] - MR);                            \
    float f6 = ex2(S[3][2] - MR), f7 = ex2(S[3][3] - MR);                            \
    float sm = (((e0 + e1) + (e2 + e3)) + ((e4 + e5) + (e6 + e7)))                   \
             + (((f0 + f1) + (f2 + f3)) + ((f4 + f5) + (f6 + f7)));                  \
    sm += __shfl_xor(sm, 16, 64);                                                    \
    sm += __shfl_xor(sm, 32, 64);                                                    \
    LR += sm;                                                                        \
    bool odd = (g & 1);                                                              \
    {                                                                                \
      u32 w0 = pk2(e0, e1), w1 = pk2(e2, e3), w2 = pk2(e4, e5), w3 = pk2(e6, e7);    \
      u32 x0 = __shfl_xor(w0, 16, 64), x1 = __shfl_xor(w1, 16, 64);                  \
      u32 x2 = __shfl_xor(w2, 16, 64), x3 = __shfl_xor(w3, 16, 64);                  \
      u32x4 pw;                                                                      \
      pw.x = odd ? x2 : w0; pw.y = odd ? x3 : w1;                                    \
      pw.z = odd ? w2 : x0; pw.w = odd ? w3 : x1;                                    \
      PA = __builtin_bit_cast(bf16x8, pw);                                           \
    }                                                                                \
    {                                                                                \
      u32 w0 = pk2(f0, f1), w1 = pk2(f2, f3), w2 = pk2(f4, f5), w3 = pk2(f6, f7);    \
      u32 x0 = __shfl_xor(w0, 16, 64), x1 = __shfl_xor(w1, 16, 64);                  \
      u32 x2 = __shfl_xor(w2, 16, 64), x3 = __shfl_xor(w3, 16, 64);                  \
      u32x4 pw;                                                                      \
      pw.x = odd ? x2 : w0; pw.y = odd ? x3 : w1;                                    \
      pw.z = odd ? w2 : x0; pw.w = odd ? w3 : x1;                                    \
      PB = __builtin_bit_cast(bf16x8, pw);                                           \
    }                                                                                \
  }

  // ---- prologue: stage tiles 0,1 (12 loads in flight) ----
  STAGE(0, key_base)
  STAGE(1, key_base + 64)

  int cur = 0;  // ring buffer holding tile i
  for (int i = 0; i < NWIN; ++i) {
    if (i < NWIN - 1) {
      asm volatile("s_waitcnt vmcnt(6)" ::: "memory");  // tile i landed; tile i+1 in flight
    } else {
      asm volatile("s_waitcnt vmcnt(0)" ::: "memory");
    }
    __builtin_amdgcn_s_barrier();  // all waves' tile-i DMAs + prior-window reads done
    if (i + 2 < NWIN) {
      int nx = cur + 2; nx = (nx >= 3) ? nx - 3 : nx;
      STAGE(nx, key_base + (i + 2) * 64)
    }

    const u16* kb = kbuf[cur];
    const u16* vb = vbuf[cur];

    // ---- QK^T swapped, 64 keys x 32 q-rows: each K-frag read feeds both q-groups ----
    f32x4 sg0[4], sg1[4];
#pragma unroll
    for (int st = 0; st < 4; ++st) {
      sg0[st] = (f32x4){0.f, 0.f, 0.f, 0.f};
      sg1[st] = (f32x4){0.f, 0.f, 0.f, 0.f};
    }
    __builtin_amdgcn_s_setprio(1);
#pragma unroll
    for (int kf = 0; kf < 4; ++kf) {
      int cs = ((kf * 4 + g) ^ l16) << 3;
#pragma unroll
      for (int st = 0; st < 4; ++st) {
        const u16* kp = kb + (st * 16 + l16) * 128 + cs;
        bf16x8 kh = *(const bf16x8*)(const void*)kp;
        bf16x8 kl = *(const bf16x8*)(const void*)(kp + 8192);
        sg0[st] = MFMA(kh, qh0[kf], sg0[st], 0, 0, 0);
        sg0[st] = MFMA(kh, ql0[kf], sg0[st], 0, 0, 0);
        sg0[st] = MFMA(kl, qh0[kf], sg0[st], 0, 0, 0);
        sg1[st] = MFMA(kh, qh1[kf], sg1[st], 0, 0, 0);
        sg1[st] = MFMA(kh, ql1[kf], sg1[st], 0, 0, 0);
        sg1[st] = MFMA(kl, qh1[kf], sg1[st], 0, 0, 0);
      }
    }
    __builtin_amdgcn_s_setprio(0);

    // ---- softmax + P-pack, one chain per group per 64 keys ----
    bf16x8 pa0A, pa0B, pa1A, pa1B;
    SMPACK(sg0, m0, l0, acc0, pa0A, pa0B)
    SMPACK(sg1, m1, l1, acc1, pa1A, pa1B)

    // ---- PV: one V-frag pair feeds both q-groups ----
    __builtin_amdgcn_s_setprio(1);
#pragma unroll
    for (int nf = 0; nf < 8; ++nf) {
      int d = nf * 16 + l16;
      int sw = (d >> 1) & 7;
      const u16* vr = vb + d * 64;
      bf16x8 vf0 = *(const bf16x8*)(const void*)(vr + ((mg ^ sw) << 3));
      bf16x8 vf1 = *(const bf16x8*)(const void*)(vr + (((4 + mg) ^ sw) << 3));
      acc0[nf] = MFMA(pa0A, vf0, acc0[nf], 0, 0, 0);
      acc0[nf] = MFMA(pa0B, vf1, acc0[nf], 0, 0, 0);
      acc1[nf] = MFMA(pa1A, vf0, acc1[nf], 0, 0, 0);
      acc1[nf] = MFMA(pa1B, vf1, acc1[nf], 0, 0, 0);
    }
    __builtin_amdgcn_s_setprio(0);

    cur = (cur + 1 >= 3) ? cur - 2 : cur + 1;
  }

  // ---- write partials (m, l, O) for the 2 16-row groups ----
  const int pidx0 = sp * NQG + (gr0 >> 4);
  {
    u16* po = PO + (size_t)pidx0 * 16 * DIM;
#pragma unroll
    for (int nf = 0; nf < 8; ++nf)
#pragma unroll
      for (int r = 0; r < 4; ++r)
        po[(g * 4 + r) * DIM + nf * 16 + l16] = f2bu(acc0[nf][r]);
    u16* po1 = PO + (size_t)(pidx0 + 1) * 16 * DIM;
#pragma unroll
    for (int nf = 0; nf < 8; ++nf)
#pragma unroll
      for (int r = 0; r < 4; ++r)
        po1[(g * 4 + r) * DIM + nf * 16 + l16] = f2bu(acc1[nf][r]);
  }
  if (g == 0) { Pm[pidx0 * 16 + l16] = m0; Pl[pidx0 * 16 + l16] = l0; }
  if (g == 1) { Pm[(pidx0 + 1) * 16 + l16] = m1; Pl[(pidx0 + 1) * 16 + l16] = l1; }

  // ---- last-arriver combine for this qb (release/acquire across XCDs) ----
  __threadfence();  // release: partials visible device-wide before count
  if (tid == 0) ticket = atomicAdd(&cnt[qb], 1);
  __syncthreads();
  if (ticket != NSP - 1) return;
  __threadfence();  // acquire: all 8 splits' partials now visible

  // scale table: thread r (0..255) handles row r of this qb
  if (tid < 256) {
    const int qg = qb * 16 + (tid >> 4);
    const int rr = tid & 15;
    float m = -1e30f;
#pragma unroll
    for (int s = 0; s < NSP; ++s) m = fmaxf(m, Pm[(s * NQG + qg) * 16 + rr]);
    float den = 0.f;
    float e[NSP];
#pragma unroll
    for (int s = 0; s < NSP; ++s) {
      e[s] = ex2(Pm[(s * NQG + qg) * 16 + rr] - m);
      den += Pl[(s * NQG + qg) * 16 + rr] * e[s];
    }
    float inv = 1.0f / den;
#pragma unroll
    for (int s = 0; s < NSP; ++s) scl[s][tid] = e[s] * inv;
  }
  __syncthreads();

  // combine 256 rows x 128 cols: 8 iters x 512 thr x 8 elems
#pragma unroll
  for (int it = 0; it < 8; ++it) {
    const int idx = it * 4096 + tid * 8;
    const int row = idx >> 7;  // 0..255
    const int qg = qb * 16 + (row >> 4);
    const int rl = row & 15;
    const int col = idx & 127;
    float a[8];
#pragma unroll
    for (int j = 0; j < 8; ++j) a[j] = 0.f;
#pragma unroll
    for (int s = 0; s < NSP; ++s) {
      u16x8 p = *(const u16x8*)(const void*)(PO + ((size_t)((s * NQG + qg) * 16 + rl)) * DIM + col);
      float wgt = scl[s][row];
#pragma unroll
      for (int j = 0; j < 8; ++j) a[j] += bu2f(p[j]) * wgt;
    }
    float* op = out + ((size_t)qb * 256 + row) * DIM + col;
    f32x4 o0 = {a[0], a[1], a[2], a[3]};
    f32x4 o1 = {a[4], a[5], a[6], a[7]};
    *(f32x4*)op = o0;
    *(f32x4*)(op + 4) = o1;
  }
#undef STAGE
#undef SMPACK
}

extern "C" void kernel_launch(void* const* d_in, const int* in_sizes, int n_in,
                              void* d_out, int out_size, void* d_ws, size_t ws_size,
                              hipStream_t stream) {
  const float* X  = (const float*)d_in[0];
  const float* wq = (const float*)d_in[4];
  const float* wk = (const float*)d_in[5];
  const float* wv = (const float*)d_in[6];
  float* out = (float*)d_out;

  u16* WT = (u16*)d_ws;                       // 3*2*128*128 u16 = 192 KiB
  u16* Qh = WT + 3 * 2 * 128 * 128;
  u16* Ql = Qh + (size_t)BATCH * S_SRC * DIM; // 2 MiB each
  u16* Kh = Ql + (size_t)BATCH * S_SRC * DIM;
  u16* Kl = Kh + (size_t)BATCH * S_SRC * DIM;
  u16* VT = Kl + (size_t)BATCH * S_SRC * DIM; // [B][D][S]
  float* Pm = (float*)(VT + (size_t)BATCH * S_SRC * DIM);  // [NSP*NQG*16] f32
  float* Pl = Pm + (size_t)NSP * NQG * 16;
  u16* PO = (u16*)(Pl + (size_t)NSP * NQG * 16);           // [NSP*NQG*16*128] bf16 = 16 MiB
  int* cnt = (int*)(PO + (size_t)NSP * NQG * 16 * DIM);    // [NQB] arrival counters

  hipMemsetAsync(cnt, 0, NQB * sizeof(int), stream);       // re-zeroed every replay
  hipLaunchKernelGGL(k_wsplit, dim3(192), dim3(256), 0, stream, wq, wk, wv, WT);
  hipLaunchKernelGGL(k_proj, dim3(BATCH * S_SRC / 32), dim3(256), 0, stream,
                     X, WT, Qh, Ql, Kh, Kl, VT);
  hipLaunchKernelGGL(k_attn, dim3(NQB * NSP), dim3(512), 0, stream,
                     Qh, Ql, Kh, Kl, VT, Pm, Pl, PO, cnt, out);
}

// Round 15
// 71.606 us; speedup vs baseline: 2.1485x; 2.1485x over previous
//
#include <hip/hip_runtime.h>
#include <hip/hip_bf16.h>

#define S_SRC 4096
#define DIM 128
#define BATCH 2
#define NSP 8
#define NQB 32    // 256-row q-blocks
#define NQG 512   // 16-row q-groups total
#define NWIN 8    // (S_SRC/NSP)/64 key windows per split

typedef unsigned short u16;
typedef unsigned int u32;
typedef __bf16 bf16x8 __attribute__((ext_vector_type(8)));
typedef float f32x4 __attribute__((ext_vector_type(4)));
typedef u32 u32x4 __attribute__((ext_vector_type(4)));
typedef u16 u16x8 __attribute__((ext_vector_type(8)));

__device__ __forceinline__ __bf16 bf_hi(float x) { return (__bf16)x; }
__device__ __forceinline__ __bf16 bf_lo(float x, __bf16 h) { return (__bf16)(x - (float)h); }
__device__ __forceinline__ u16 bfu(__bf16 h) { return __builtin_bit_cast(u16, h); }
__device__ __forceinline__ u16 f2bu(float x) { return __builtin_bit_cast(u16, (__bf16)x); }
__device__ __forceinline__ float bu2f(u16 u) { return (float)__builtin_bit_cast(__bf16, u); }
__device__ __forceinline__ u32 pk2(float lo, float hi) {
  return (u32)f2bu(lo) | ((u32)f2bu(hi) << 16);
}
// native exp2: v_exp_f32 IS 2^x on AMD — single TRANS instruction, no pre-multiply
__device__ __forceinline__ float ex2(float x) {
  float r;
  asm("v_exp_f32 %0, %1" : "=v"(r) : "v"(x));
  return r;
}
__device__ __forceinline__ void g2l16(const u16* src, u16* ldst) {
  __builtin_amdgcn_global_load_lds((const __attribute__((address_space(1))) void*)src,
                                   (__attribute__((address_space(3))) void*)ldst, 16, 0, 0);
}
#define MFMA __builtin_amdgcn_mfma_f32_16x16x32_bf16

// ---------------- kernel 1: QKV projection with in-block W split (k_wsplit fused) ----------------
// Each block stages W_mat (128x128 f32) into padded LDS [e][136] hi/lo bf16 (transposed),
// folding log2(e)/sqrt(128) into Wq so softmax exponentials run in base-2.
__global__ __launch_bounds__(256) void k_proj(const float* __restrict__ X,
                                              const float* __restrict__ wq,
                                              const float* __restrict__ wk,
                                              const float* __restrict__ wv,
                                              u16* __restrict__ Qh, u16* __restrict__ Ql,
                                              u16* __restrict__ Kh, u16* __restrict__ Kl,
                                              u16* __restrict__ VT) {
  const int b = blockIdx.x >> 7;
  const int tile = blockIdx.x & 127;
  const int tid = threadIdx.x;
  const int w = tid >> 6, lane = tid & 63, g = lane >> 4, l16 = lane & 15;

  __shared__ alignas(16) u16 wl[2][128 * 136];  // [hi/lo][e*136 + d], 68KB

  bf16x8 a_h[2][4], a_l[2][4];
#pragma unroll
  for (int mf = 0; mf < 2; ++mf) {
    int row = tile * 32 + mf * 16 + l16;
    const float* xr = X + ((size_t)b * S_SRC + row) * DIM;
#pragma unroll
    for (int kf = 0; kf < 4; ++kf) {
      int d0 = kf * 32 + g * 8;
      f32x4 x0 = *(const f32x4*)(xr + d0);
      f32x4 x1 = *(const f32x4*)(xr + d0 + 4);
#pragma unroll
      for (int j = 0; j < 4; ++j) {
        __bf16 h0 = bf_hi(x0[j]);
        __bf16 h1 = bf_hi(x1[j]);
        a_h[mf][kf][j] = h0;
        a_l[mf][kf][j] = bf_lo(x0[j], h0);
        a_h[mf][kf][4 + j] = h1;
        a_l[mf][kf][4 + j] = bf_lo(x1[j], h1);
      }
    }
  }

#pragma unroll 1
  for (int mat = 0; mat < 3; ++mat) {
    const float* wsrc = (mat == 0) ? wq : ((mat == 1) ? wk : wv);
    if (mat) __syncthreads();  // previous mat's frag reads done before overwrite
    for (int i = tid; i < 16384; i += 256) {
      int d = i >> 7, e = i & 127;  // W is [d][e] row-major
      float x = wsrc[i];
      if (mat == 0) x *= 0.12751744684693238f;  // log2(e) / sqrt(128)
      __bf16 h = bf_hi(x);
      wl[0][e * 136 + d] = bfu(h);
      wl[1][e * 136 + d] = bfu(bf_lo(x, h));
    }
    __syncthreads();

#pragma unroll
    for (int nf = 0; nf < 2; ++nf) {
      int col = w * 32 + nf * 16 + l16;
      f32x4 acc[2];
      acc[0] = (f32x4){0.f, 0.f, 0.f, 0.f};
      acc[1] = (f32x4){0.f, 0.f, 0.f, 0.f};
#pragma unroll
      for (int kf = 0; kf < 4; ++kf) {
        int d0 = kf * 32 + g * 8;
        bf16x8 bh = *(const bf16x8*)(const void*)(&wl[0][col * 136 + d0]);
        bf16x8 bl = *(const bf16x8*)(const void*)(&wl[1][col * 136 + d0]);
#pragma unroll
        for (int mf = 0; mf < 2; ++mf) {
          acc[mf] = MFMA(a_h[mf][kf], bh, acc[mf], 0, 0, 0);
          acc[mf] = MFMA(a_h[mf][kf], bl, acc[mf], 0, 0, 0);
          acc[mf] = MFMA(a_l[mf][kf], bh, acc[mf], 0, 0, 0);
        }
      }
#pragma unroll
      for (int mf = 0; mf < 2; ++mf)
#pragma unroll
        for (int r = 0; r < 4; ++r) {
          int row = tile * 32 + mf * 16 + g * 4 + r;
          float v = acc[mf][r];
          if (mat == 2) {
            VT[((size_t)b * DIM + col) * S_SRC + row] = f2bu(v);
          } else {
            __bf16 h = bf_hi(v);
            __bf16 l = bf_lo(v, h);
            size_t o = ((size_t)b * S_SRC + row) * DIM + col;
            if (mat == 0) { Qh[o] = bfu(h); Ql[o] = bfu(l); }
            else          { Kh[o] = bfu(h); Kl[o] = bfu(l); }
          }
        }
    }
  }
}

// ---------------- kernel 2: flash attention, 64-key windows, 3-deep ring ----------------
// Swapped QK^T (A=K, B=Q). Per wave: 2 q-groups of 16 rows. 8 windows of 64 keys.
// Scores are in log2 domain (log2e folded into Wq); all exponentials are v_exp_f32.
__global__ __launch_bounds__(512, 2) void k_attn(const u16* __restrict__ Qh, const u16* __restrict__ Ql,
                                                 const u16* __restrict__ Kh, const u16* __restrict__ Kl,
                                                 const u16* __restrict__ VT,
                                                 float* __restrict__ Pm, float* __restrict__ Pl,
                                                 u16* __restrict__ PO) {
  const int bid = blockIdx.x;
  const int sp = bid & 7;     // kv split 0..7 (== XCD id)
  const int qb = bid >> 3;    // 256-row q-block 0..31
  const int b = qb >> 4;
  const int tid = threadIdx.x;
  const int w = tid >> 6, lane = tid & 63, g = lane >> 4, l16 = lane & 15;

  __shared__ alignas(16) u16 kbuf[3][16384];  // 96KB: [hi 64x128 | lo 64x128] chunk-swizzled
  __shared__ alignas(16) u16 vbuf[3][8192];   // 48KB: [128d x 64s] chunk-swizzled

  // ---- Q fragments (hi/lo), 32 q-rows: 2 groups of 16 ----
  const int gr0 = qb * 256 + w * 32;
  bf16x8 qh0[4], ql0[4], qh1[4], ql1[4];
  {
    const u16* p0h = Qh + ((size_t)gr0 + l16) * DIM;
    const u16* p0l = Ql + ((size_t)gr0 + l16) * DIM;
    const u16* p1h = Qh + ((size_t)gr0 + 16 + l16) * DIM;
    const u16* p1l = Ql + ((size_t)gr0 + 16 + l16) * DIM;
#pragma unroll
    for (int kf = 0; kf < 4; ++kf) {
      int d0 = kf * 32 + g * 8;
      qh0[kf] = *(const bf16x8*)(const void*)(p0h + d0);
      ql0[kf] = *(const bf16x8*)(const void*)(p0l + d0);
      qh1[kf] = *(const bf16x8*)(const void*)(p1h + d0);
      ql1[kf] = *(const bf16x8*)(const void*)(p1l + d0);
    }
  }

  f32x4 acc0[8], acc1[8];
#pragma unroll
  for (int nf = 0; nf < 8; ++nf) {
    acc0[nf] = (f32x4){0.f, 0.f, 0.f, 0.f};
    acc1[nf] = (f32x4){0.f, 0.f, 0.f, 0.f};
  }
  float m0 = -1e30f, m1 = -1e30f, l0 = 0.f, l1 = 0.f;

  const int key_base = sp * (S_SRC / NSP);
  const u16* KhB = Kh + (size_t)b * S_SRC * DIM;
  const u16* KlB = Kl + (size_t)b * S_SRC * DIM;
  const u16* VTB = VT + (size_t)b * DIM * S_SRC;

  // staging (512 threads x 6 chunks of 16B), chunk-XOR swizzle
  const int kkey0 = tid >> 4;                           // key row 0..31 (pass0); +32 pass1
  const int kks = ((tid & 15) ^ (kkey0 & 15)) << 3;     // swizzled source d-offset (elems)
  const int vd0 = tid >> 3;                             // V d-row 0..63 (pass0); +64 pass1
  const int vks = ((tid & 7) ^ ((vd0 >> 1) & 7)) << 3;  // swizzled source s-offset (elems)
  const int wb = w * 512;                               // wave-uniform LDS chunk base (u16)
  const int mg = ((g & 1) << 1) | (g >> 1);             // V key-chunk permutation {0,2,1,3}

#define STAGE(BUF, KEY0)                                                             \
  {                                                                                  \
    g2l16(KhB + ((size_t)((KEY0) + kkey0)) * DIM + kks,      &kbuf[BUF][wb]);        \
    g2l16(KhB + ((size_t)((KEY0) + 32 + kkey0)) * DIM + kks, &kbuf[BUF][4096 + wb]); \
    g2l16(KlB + ((size_t)((KEY0) + kkey0)) * DIM + kks,      &kbuf[BUF][8192 + wb]); \
    g2l16(KlB + ((size_t)((KEY0) + 32 + kkey0)) * DIM + kks, &kbuf[BUF][12288 + wb]);\
    g2l16(VTB + (size_t)vd0 * S_SRC + (KEY0) + vks,          &vbuf[BUF][wb]);        \
    g2l16(VTB + (size_t)(64 + vd0) * S_SRC + (KEY0) + vks,   &vbuf[BUF][4096 + wb]); \
  }

// S = f32x4[4] score array (keys st*16 + g*4 + r of q-col l16), MR/LR running stats,
// ACC = f32x4[8] output acc, PA/PB = packed P A-frags for key-chunks 0/1.
#define SMPACK(S, MR, LR, ACC, PA, PB)                                               \
  {                                                                                  \
    float mxa = fmaxf(fmaxf(fmaxf(S[0][0], S[0][1]), fmaxf(S[0][2], S[0][3])),       \
                      fmaxf(fmaxf(S[1][0], S[1][1]), fmaxf(S[1][2], S[1][3])));      \
    float mxb = fmaxf(fmaxf(fmaxf(S[2][0], S[2][1]), fmaxf(S[2][2], S[2][3])),       \
                      fmaxf(fmaxf(S[3][0], S[3][1]), fmaxf(S[3][2], S[3][3])));      \
    float mx = fmaxf(mxa, mxb);                                                      \
    mx = fmaxf(mx, __shfl_xor(mx, 16, 64));                                          \
    mx = fmaxf(mx, __shfl_xor(mx, 32, 64));                                          \
    if (!__all(mx - MR <= 11.5f)) {                                                  \
      float mn = fmaxf(MR, mx);                                                      \
      float f = ex2(MR - mn);                                                        \
      LR *= f; MR = mn;                                                              \
      float fr0 = __shfl(f, g * 4 + 0, 64);                                          \
      float fr1 = __shfl(f, g * 4 + 1, 64);                                          \
      float fr2 = __shfl(f, g * 4 + 2, 64);                                          \
      float fr3 = __shfl(f, g * 4 + 3, 64);                                          \
      _Pragma("unroll")                                                              \
      for (int nf = 0; nf < 8; ++nf) {                                               \
        ACC[nf][0] *= fr0; ACC[nf][1] *= fr1;                                        \
        ACC[nf][2] *= fr2; ACC[nf][3] *= fr3;                                        \
      }                                                                              \
    }                                                                                \
    float e0 = ex2(S[0][0] - MR), e1 = ex2(S[0][1] - MR);                            \
    float e2 = ex2(S[0][2] - MR), e3 = ex2(S[0][3] - MR);                            \
    float e4 = ex2(S[1][0] - MR), e5 = ex2(S[1][1] - MR);                            \
    float e6 = ex2(S[1][2] - MR), e7 = ex2(S[1][3] - MR);                            \
    float f0 = ex2(S[2][0] - MR), f1 = ex2(S[2][1] - MR);                            \
    float f2 = ex2(S[2][2] - MR), f3 = ex2(S[2][3] - MR);                            \
    float f4 = ex2(S[3][0] - MR), f5 = ex2(S[3][1] - MR);                            \
    float f6 = ex2(S[3][2] - MR), f7 = ex2(S[3][3] - MR);                            \
    float sm = (((e0 + e1) + (e2 + e3)) + ((e4 + e5) + (e6 + e7)))                   \
             + (((f0 + f1) + (f2 + f3)) + ((f4 + f5) + (f6 + f7)));                  \
    sm += __shfl_xor(sm, 16, 64);                                                    \
    sm += __shfl_xor(sm, 32, 64);                                                    \
    LR += sm;                                                                        \
    bool odd = (g & 1);                                                              \
    {                                                                                \
      u32 w0 = pk2(e0, e1), w1 = pk2(e2, e3), w2 = pk2(e4, e5), w3 = pk2(e6, e7);    \
      u32 x0 = __shfl_xor(w0, 16, 64), x1 = __shfl_xor(w1, 16, 64);                  \
      u32 x2 = __shfl_xor(w2, 16, 64), x3 = __shfl_xor(w3, 16, 64);                  \
      u32x4 pw;                                                                      \
      pw.x = odd ? x2 : w0; pw.y = odd ? x3 : w1;                                    \
      pw.z = odd ? w2 : x0; pw.w = odd ? w3 : x1;                                    \
      PA = __builtin_bit_cast(bf16x8, pw);                                           \
    }                                                                                \
    {                                                                                \
      u32 w0 = pk2(f0, f1), w1 = pk2(f2, f3), w2 = pk2(f4, f5), w3 = pk2(f6, f7);    \
      u32 x0 = __shfl_xor(w0, 16, 64), x1 = __shfl_xor(w1, 16, 64);                  \
      u32 x2 = __shfl_xor(w2, 16, 64), x3 = __shfl_xor(w3, 16, 64);                  \
      u32x4 pw;                                                                      \
      pw.x = odd ? x2 : w0; pw.y = odd ? x3 : w1;                                    \
      pw.z = odd ? w2 : x0; pw.w = odd ? w3 : x1;                                    \
      PB = __builtin_bit_cast(bf16x8, pw);                                           \
    }                                                                                \
  }

  // ---- prologue: stage tiles 0,1 (12 loads in flight) ----
  STAGE(0, key_base)
  STAGE(1, key_base + 64)

  int cur = 0;  // ring buffer holding tile i
  for (int i = 0; i < NWIN; ++i) {
    if (i < NWIN - 1) {
      asm volatile("s_waitcnt vmcnt(6)" ::: "memory");  // tile i landed; tile i+1 in flight
    } else {
      asm volatile("s_waitcnt vmcnt(0)" ::: "memory");
    }
    __builtin_amdgcn_s_barrier();  // all waves' tile-i DMAs + prior-window reads done
    if (i + 2 < NWIN) {
      int nx = cur + 2; nx = (nx >= 3) ? nx - 3 : nx;
      STAGE(nx, key_base + (i + 2) * 64)
    }

    const u16* kb = kbuf[cur];
    const u16* vb = vbuf[cur];

    // ---- QK^T swapped, 64 keys x 32 q-rows: each K-frag read feeds both q-groups ----
    f32x4 sg0[4], sg1[4];
#pragma unroll
    for (int st = 0; st < 4; ++st) {
      sg0[st] = (f32x4){0.f, 0.f, 0.f, 0.f};
      sg1[st] = (f32x4){0.f, 0.f, 0.f, 0.f};
    }
    __builtin_amdgcn_s_setprio(1);
#pragma unroll
    for (int kf = 0; kf < 4; ++kf) {
      int cs = ((kf * 4 + g) ^ l16) << 3;
#pragma unroll
      for (int st = 0; st < 4; ++st) {
        const u16* kp = kb + (st * 16 + l16) * 128 + cs;
        bf16x8 kh = *(const bf16x8*)(const void*)kp;
        bf16x8 kl = *(const bf16x8*)(const void*)(kp + 8192);
        sg0[st] = MFMA(kh, qh0[kf], sg0[st], 0, 0, 0);
        sg0[st] = MFMA(kh, ql0[kf], sg0[st], 0, 0, 0);
        sg0[st] = MFMA(kl, qh0[kf], sg0[st], 0, 0, 0);
        sg1[st] = MFMA(kh, qh1[kf], sg1[st], 0, 0, 0);
        sg1[st] = MFMA(kh, ql1[kf], sg1[st], 0, 0, 0);
        sg1[st] = MFMA(kl, qh1[kf], sg1[st], 0, 0, 0);
      }
    }
    __builtin_amdgcn_s_setprio(0);

    // ---- softmax + P-pack, one chain per group per 64 keys ----
    bf16x8 pa0A, pa0B, pa1A, pa1B;
    SMPACK(sg0, m0, l0, acc0, pa0A, pa0B)
    SMPACK(sg1, m1, l1, acc1, pa1A, pa1B)

    // ---- PV: one V-frag pair feeds both q-groups ----
    __builtin_amdgcn_s_setprio(1);
#pragma unroll
    for (int nf = 0; nf < 8; ++nf) {
      int d = nf * 16 + l16;
      int sw = (d >> 1) & 7;
      const u16* vr = vb + d * 64;
      bf16x8 vf0 = *(const bf16x8*)(const void*)(vr + ((mg ^ sw) << 3));
      bf16x8 vf1 = *(const bf16x8*)(const void*)(vr + (((4 + mg) ^ sw) << 3));
      acc0[nf] = MFMA(pa0A, vf0, acc0[nf], 0, 0, 0);
      acc0[nf] = MFMA(pa0B, vf1, acc0[nf], 0, 0, 0);
      acc1[nf] = MFMA(pa1A, vf0, acc1[nf], 0, 0, 0);
      acc1[nf] = MFMA(pa1B, vf1, acc1[nf], 0, 0, 0);
    }
    __builtin_amdgcn_s_setprio(0);

    cur = (cur + 1 >= 3) ? cur - 2 : cur + 1;
  }

  // ---- write partials (m, l, O) for the 2 16-row groups ----
  const int pidx0 = sp * NQG + (gr0 >> 4);
  {
    u16* po = PO + (size_t)pidx0 * 16 * DIM;
#pragma unroll
    for (int nf = 0; nf < 8; ++nf)
#pragma unroll
      for (int r = 0; r < 4; ++r)
        po[(g * 4 + r) * DIM + nf * 16 + l16] = f2bu(acc0[nf][r]);
    u16* po1 = PO + (size_t)(pidx0 + 1) * 16 * DIM;
#pragma unroll
    for (int nf = 0; nf < 8; ++nf)
#pragma unroll
      for (int r = 0; r < 4; ++r)
        po1[(g * 4 + r) * DIM + nf * 16 + l16] = f2bu(acc1[nf][r]);
  }
  if (g == 0) { Pm[pidx0 * 16 + l16] = m0; Pl[pidx0 * 16 + l16] = l0; }
  if (g == 1) { Pm[(pidx0 + 1) * 16 + l16] = m1; Pl[(pidx0 + 1) * 16 + l16] = l1; }
#undef STAGE
#undef SMPACK
}

// ---------------- kernel 3: combine KV-split partials (wide loads, 256 thr) ----------------
__global__ __launch_bounds__(256) void k_comb(const float* __restrict__ Pm,
                                              const float* __restrict__ Pl,
                                              const u16* __restrict__ PO,
                                              float* __restrict__ out) {
  const int qg = blockIdx.x;
  const int tid = threadIdx.x;

  __shared__ float sc[NSP][16];  // [split][row]
  if (tid < 16) {
    float m = -1e30f;
#pragma unroll
    for (int s = 0; s < NSP; ++s) m = fmaxf(m, Pm[(s * NQG + qg) * 16 + tid]);
    float den = 0.f;
#pragma unroll
    for (int s = 0; s < NSP; ++s) {
      float e = exp2f(Pm[(s * NQG + qg) * 16 + tid] - m);  // log2-domain stats (cold path)
      sc[s][tid] = e;
      den += Pl[(s * NQG + qg) * 16 + tid] * e;
    }
    float inv = 1.0f / den;
#pragma unroll
    for (int s = 0; s < NSP; ++s) sc[s][tid] *= inv;
  }
  __syncthreads();

  // 2048 elems / 256 thr = 8 per thread (one u16x8 per split, two f32x4 stores)
  const int e0 = tid * 8;
  const int row = e0 >> 7;
  float a[8];
#pragma unroll
  for (int j = 0; j < 8; ++j) a[j] = 0.f;
#pragma unroll
  for (int s = 0; s < NSP; ++s) {
    u16x8 p = *(const u16x8*)(const void*)(PO + (size_t)(s * NQG + qg) * 16 * DIM + e0);
    float wgt = sc[s][row];
#pragma unroll
    for (int j = 0; j < 8; ++j) a[j] += bu2f(p[j]) * wgt;
  }
  float* op = out + (size_t)qg * 16 * DIM + e0;
  f32x4 o0 = {a[0], a[1], a[2], a[3]};
  f32x4 o1 = {a[4], a[5], a[6], a[7]};
  *(f32x4*)op = o0;
  *(f32x4*)(op + 4) = o1;
}

extern "C" void kernel_launch(void* const* d_in, const int* in_sizes, int n_in,
                              void* d_out, int out_size, void* d_ws, size_t ws_size,
                              hipStream_t stream) {
  const float* X  = (const float*)d_in[0];
  const float* wq = (const float*)d_in[4];
  const float* wk = (const float*)d_in[5];
  const float* wv = (const float*)d_in[6];
  float* out = (float*)d_out;

  u16* Qh = (u16*)d_ws;                       // 2 MiB each
  u16* Ql = Qh + (size_t)BATCH * S_SRC * DIM;
  u16* Kh = Ql + (size_t)BATCH * S_SRC * DIM;
  u16* Kl = Kh + (size_t)BATCH * S_SRC * DIM;
  u16* VT = Kl + (size_t)BATCH * S_SRC * DIM; // [B][D][S]
  float* Pm = (float*)(VT + (size_t)BATCH * S_SRC * DIM);  // [NSP*NQG*16] f32
  float* Pl = Pm + (size_t)NSP * NQG * 16;
  u16* PO = (u16*)(Pl + (size_t)NSP * NQG * 16);           // [NSP*NQG*16*128] bf16 = 16 MiB

  hipLaunchKernelGGL(k_proj, dim3(BATCH * S_SRC / 32), dim3(256), 0, stream,
                     X, wq, wk, wv, Qh, Ql, Kh, Kl, VT);
  hipLaunchKernelGGL(k_attn, dim3(NQB * NSP), dim3(512), 0, stream,
                     Qh, Ql, Kh, Kl, VT, Pm, Pl, PO);
  hipLaunchKernelGGL(k_comb, dim3(NQG), dim3(256), 0, stream, Pm, Pl, PO, out);
}

// Round 16
// 67.878 us; speedup vs baseline: 2.2665x; 1.0549x over previous
//
#include <hip/hip_runtime.h>
#include <hip/hip_bf16.h>

#define S_SRC 4096
#define DIM 128
#define BATCH 2
#define NSP 8
#define NQB 32    // 256-row q-blocks
#define NQG 512   // 16-row q-groups total
#define NWIN 8    // (S_SRC/NSP)/64 key windows per split

typedef unsigned short u16;
typedef unsigned int u32;
typedef __bf16 bf16x8 __attribute__((ext_vector_type(8)));
typedef float f32x4 __attribute__((ext_vector_type(4)));
typedef u32 u32x4 __attribute__((ext_vector_type(4)));
typedef u16 u16x8 __attribute__((ext_vector_type(8)));

__device__ __forceinline__ __bf16 bf_hi(float x) { return (__bf16)x; }
__device__ __forceinline__ __bf16 bf_lo(float x, __bf16 h) { return (__bf16)(x - (float)h); }
__device__ __forceinline__ u16 bfu(__bf16 h) { return __builtin_bit_cast(u16, h); }
__device__ __forceinline__ u16 f2bu(float x) { return __builtin_bit_cast(u16, (__bf16)x); }
__device__ __forceinline__ float bu2f(u16 u) { return (float)__builtin_bit_cast(__bf16, u); }
__device__ __forceinline__ u32 pk2(float lo, float hi) {
  return (u32)f2bu(lo) | ((u32)f2bu(hi) << 16);
}
// native exp2: v_exp_f32 IS 2^x on AMD — single TRANS instruction, no pre-multiply
__device__ __forceinline__ float ex2(float x) {
  float r;
  asm("v_exp_f32 %0, %1" : "=v"(r) : "v"(x));
  return r;
}
__device__ __forceinline__ void g2l16(const u16* src, u16* ldst) {
  __builtin_amdgcn_global_load_lds((const __attribute__((address_space(1))) void*)src,
                                   (__attribute__((address_space(3))) void*)ldst, 16, 0, 0);
}
#define MFMA __builtin_amdgcn_mfma_f32_16x16x32_bf16

// ---------------- kernel 0: transpose + hi/lo split the weight matrices ----------------
// Wq also folds log2(e)/sqrt(128) so all softmax exponentials run in base-2 (v_exp_f32).
__global__ __launch_bounds__(256) void k_wsplit(const float* __restrict__ wq,
                                                const float* __restrict__ wk,
                                                const float* __restrict__ wv,
                                                u16* __restrict__ wt) {
  int idx = blockIdx.x * 256 + threadIdx.x;  // 3*128*128 = 49152
  int mat = idx >> 14;
  int r = idx & 16383;
  int d = r >> 7, e = r & 127;
  const float* w = (mat == 0) ? wq : ((mat == 1) ? wk : wv);
  float x = w[r];
  if (mat == 0) x *= 0.12751744684693238f;  // log2(e) / sqrt(128)
  __bf16 h = bf_hi(x);
  __bf16 l = bf_lo(x, h);
  wt[((mat * 2 + 0) * 128 + e) * 128 + d] = bfu(h);
  wt[((mat * 2 + 1) * 128 + e) * 128 + d] = bfu(l);
}

// ---------------- kernel 1: QKV projection (fused 3 mats, X read once) ----------------
__global__ __launch_bounds__(256) void k_proj(const float* __restrict__ X,
                                              const u16* __restrict__ wt,
                                              u16* __restrict__ Qh, u16* __restrict__ Ql,
                                              u16* __restrict__ Kh, u16* __restrict__ Kl,
                                              u16* __restrict__ VT) {
  const int b = blockIdx.x >> 7;
  const int tile = blockIdx.x & 127;
  const int tid = threadIdx.x;
  const int w = tid >> 6, lane = tid & 63, g = lane >> 4, l16 = lane & 15;

  bf16x8 a_h[2][4], a_l[2][4];
#pragma unroll
  for (int mf = 0; mf < 2; ++mf) {
    int row = tile * 32 + mf * 16 + l16;
    const float* xr = X + ((size_t)b * S_SRC + row) * DIM;
#pragma unroll
    for (int kf = 0; kf < 4; ++kf) {
      int d0 = kf * 32 + g * 8;
      f32x4 x0 = *(const f32x4*)(xr + d0);
      f32x4 x1 = *(const f32x4*)(xr + d0 + 4);
#pragma unroll
      for (int j = 0; j < 4; ++j) {
        __bf16 h0 = bf_hi(x0[j]);
        __bf16 h1 = bf_hi(x1[j]);
        a_h[mf][kf][j] = h0;
        a_l[mf][kf][j] = bf_lo(x0[j], h0);
        a_h[mf][kf][4 + j] = h1;
        a_l[mf][kf][4 + j] = bf_lo(x1[j], h1);
      }
    }
  }

#pragma unroll
  for (int mat = 0; mat < 3; ++mat) {
    const u16* wth = wt + (mat * 2 + 0) * 16384;
    const u16* wtl = wt + (mat * 2 + 1) * 16384;
#pragma unroll
    for (int nf = 0; nf < 2; ++nf) {
      int col = w * 32 + nf * 16 + l16;
      f32x4 acc[2];
      acc[0] = (f32x4){0.f, 0.f, 0.f, 0.f};
      acc[1] = (f32x4){0.f, 0.f, 0.f, 0.f};
#pragma unroll
      for (int kf = 0; kf < 4; ++kf) {
        int d0 = kf * 32 + g * 8;
        bf16x8 bh = *(const bf16x8*)(const void*)(wth + col * 128 + d0);
        bf16x8 bl = *(const bf16x8*)(const void*)(wtl + col * 128 + d0);
#pragma unroll
        for (int mf = 0; mf < 2; ++mf) {
          acc[mf] = MFMA(a_h[mf][kf], bh, acc[mf], 0, 0, 0);
          acc[mf] = MFMA(a_h[mf][kf], bl, acc[mf], 0, 0, 0);
          acc[mf] = MFMA(a_l[mf][kf], bh, acc[mf], 0, 0, 0);
        }
      }
#pragma unroll
      for (int mf = 0; mf < 2; ++mf)
#pragma unroll
        for (int r = 0; r < 4; ++r) {
          int row = tile * 32 + mf * 16 + g * 4 + r;
          float v = acc[mf][r];
          if (mat == 2) {
            VT[((size_t)b * DIM + col) * S_SRC + row] = f2bu(v);
          } else {
            __bf16 h = bf_hi(v);
            __bf16 l = bf_lo(v, h);
            size_t o = ((size_t)b * S_SRC + row) * DIM + col;
            if (mat == 0) { Qh[o] = bfu(h); Ql[o] = bfu(l); }
            else          { Kh[o] = bfu(h); Kl[o] = bfu(l); }
          }
        }
    }
  }
}

// ---------------- kernel 2: flash attention, 64-key windows, 3-deep ring ----------------
// Swapped QK^T (A=K, B=Q). Per wave: 2 q-groups of 16 rows. 8 windows of 64 keys.
// Scores are in log2 domain (log2e folded into Wq); all exponentials are v_exp_f32.
__global__ __launch_bounds__(512, 2) void k_attn(const u16* __restrict__ Qh, const u16* __restrict__ Ql,
                                                 const u16* __restrict__ Kh, const u16* __restrict__ Kl,
                                                 const u16* __restrict__ VT,
                                                 float* __restrict__ Pm, float* __restrict__ Pl,
                                                 u16* __restrict__ PO) {
  const int bid = blockIdx.x;
  const int sp = bid & 7;     // kv split 0..7 (== XCD id)
  const int qb = bid >> 3;    // 256-row q-block 0..31
  const int b = qb >> 4;
  const int tid = threadIdx.x;
  const int w = tid >> 6, lane = tid & 63, g = lane >> 4, l16 = lane & 15;

  __shared__ alignas(16) u16 kbuf[3][16384];  // 96KB: [hi 64x128 | lo 64x128] chunk-swizzled
  __shared__ alignas(16) u16 vbuf[3][8192];   // 48KB: [128d x 64s] chunk-swizzled

  // ---- Q fragments (hi/lo), 32 q-rows: 2 groups of 16 ----
  const int gr0 = qb * 256 + w * 32;
  bf16x8 qh0[4], ql0[4], qh1[4], ql1[4];
  {
    const u16* p0h = Qh + ((size_t)gr0 + l16) * DIM;
    const u16* p0l = Ql + ((size_t)gr0 + l16) * DIM;
    const u16* p1h = Qh + ((size_t)gr0 + 16 + l16) * DIM;
    const u16* p1l = Ql + ((size_t)gr0 + 16 + l16) * DIM;
#pragma unroll
    for (int kf = 0; kf < 4; ++kf) {
      int d0 = kf * 32 + g * 8;
      qh0[kf] = *(const bf16x8*)(const void*)(p0h + d0);
      ql0[kf] = *(const bf16x8*)(const void*)(p0l + d0);
      qh1[kf] = *(const bf16x8*)(const void*)(p1h + d0);
      ql1[kf] = *(const bf16x8*)(const void*)(p1l + d0);
    }
  }

  f32x4 acc0[8], acc1[8];
#pragma unroll
  for (int nf = 0; nf < 8; ++nf) {
    acc0[nf] = (f32x4){0.f, 0.f, 0.f, 0.f};
    acc1[nf] = (f32x4){0.f, 0.f, 0.f, 0.f};
  }
  float m0 = -1e30f, m1 = -1e30f, l0 = 0.f, l1 = 0.f;

  const int key_base = sp * (S_SRC / NSP);
  const u16* KhB = Kh + (size_t)b * S_SRC * DIM;
  const u16* KlB = Kl + (size_t)b * S_SRC * DIM;
  const u16* VTB = VT + (size_t)b * DIM * S_SRC;

  // staging (512 threads x 6 chunks of 16B), chunk-XOR swizzle
  const int kkey0 = tid >> 4;                           // key row 0..31 (pass0); +32 pass1
  const int kks = ((tid & 15) ^ (kkey0 & 15)) << 3;     // swizzled source d-offset (elems)
  const int vd0 = tid >> 3;                             // V d-row 0..63 (pass0); +64 pass1
  const int vks = ((tid & 7) ^ ((vd0 >> 1) & 7)) << 3;  // swizzled source s-offset (elems)
  const int wb = w * 512;                               // wave-uniform LDS chunk base (u16)
  const int mg = ((g & 1) << 1) | (g >> 1);             // V key-chunk permutation {0,2,1,3}

#define STAGE(BUF, KEY0)                                                             \
  {                                                                                  \
    g2l16(KhB + ((size_t)((KEY0) + kkey0)) * DIM + kks,      &kbuf[BUF][wb]);        \
    g2l16(KhB + ((size_t)((KEY0) + 32 + kkey0)) * DIM + kks, &kbuf[BUF][4096 + wb]); \
    g2l16(KlB + ((size_t)((KEY0) + kkey0)) * DIM + kks,      &kbuf[BUF][8192 + wb]); \
    g2l16(KlB + ((size_t)((KEY0) + 32 + kkey0)) * DIM + kks, &kbuf[BUF][12288 + wb]);\
    g2l16(VTB + (size_t)vd0 * S_SRC + (KEY0) + vks,          &vbuf[BUF][wb]);        \
    g2l16(VTB + (size_t)(64 + vd0) * S_SRC + (KEY0) + vks,   &vbuf[BUF][4096 + wb]); \
  }

// S = f32x4[4] score array (keys st*16 + g*4 + r of q-col l16), MR/LR running stats,
// ACC = f32x4[8] output acc, PA/PB = packed P A-frags for key-chunks 0/1.
#define SMPACK(S, MR, LR, ACC, PA, PB)                                               \
  {                                                                                  \
    float mxa = fmaxf(fmaxf(fmaxf(S[0][0], S[0][1]), fmaxf(S[0][2], S[0][3])),       \
                      fmaxf(fmaxf(S[1][0], S[1][1]), fmaxf(S[1][2], S[1][3])));      \
    float mxb = fmaxf(fmaxf(fmaxf(S[2][0], S[2][1]), fmaxf(S[2][2], S[2][3])),       \
                      fmaxf(fmaxf(S[3][0], S[3][1]), fmaxf(S[3][2], S[3][3])));      \
    float mx = fmaxf(mxa, mxb);                                                      \
    mx = fmaxf(mx, __shfl_xor(mx, 16, 64));                                          \
    mx = fmaxf(mx, __shfl_xor(mx, 32, 64));                                          \
    if (!__all(mx - MR <= 11.5f)) {                                                  \
      float mn = fmaxf(MR, mx);                                                      \
      float f = ex2(MR - mn);                                                        \
      LR *= f; MR = mn;                                                              \
      float fr0 = __shfl(f, g * 4 + 0, 64);                                          \
      float fr1 = __shfl(f, g * 4 + 1, 64);                                          \
      float fr2 = __shfl(f, g * 4 + 2, 64);                                          \
      float fr3 = __shfl(f, g * 4 + 3, 64);                                          \
      _Pragma("unroll")                                                              \
      for (int nf = 0; nf < 8; ++nf) {                                               \
        ACC[nf][0] *= fr0; ACC[nf][1] *= fr1;                                        \
        ACC[nf][2] *= fr2; ACC[nf][3] *= fr3;                                        \
      }                                                                              \
    }                                                                                \
    float e0 = ex2(S[0][0] - MR), e1 = ex2(S[0][1] - MR);                            \
    float e2 = ex2(S[0][2] - MR), e3 = ex2(S[0][3] - MR);                            \
    float e4 = ex2(S[1][0] - MR), e5 = ex2(S[1][1] - MR);                            \
    float e6 = ex2(S[1][2] - MR), e7 = ex2(S[1][3] - MR);                            \
    float f0 = ex2(S[2][0] - MR), f1 = ex2(S[2][1] - MR);                            \
    float f2 = ex2(S[2][2] - MR), f3 = ex2(S[2][3] - MR);                            \
    float f4 = ex2(S[3][0] - MR), f5 = ex2(S[3][1] - MR);                            \
    float f6 = ex2(S[3][2] - MR), f7 = ex2(S[3][3] - MR);                            \
    float sm = (((e0 + e1) + (e2 + e3)) + ((e4 + e5) + (e6 + e7)))                   \
             + (((f0 + f1) + (f2 + f3)) + ((f4 + f5) + (f6 + f7)));                  \
    sm += __shfl_xor(sm, 16, 64);                                                    \
    sm += __shfl_xor(sm, 32, 64);                                                    \
    LR += sm;                                                                        \
    bool odd = (g & 1);                                                              \
    {                                                                                \
      u32 w0 = pk2(e0, e1), w1 = pk2(e2, e3), w2 = pk2(e4, e5), w3 = pk2(e6, e7);    \
      u32 x0 = __shfl_xor(w0, 16, 64), x1 = __shfl_xor(w1, 16, 64);                  \
      u32 x2 = __shfl_xor(w2, 16, 64), x3 = __shfl_xor(w3, 16, 64);                  \
      u32x4 pw;                                                                      \
      pw.x = odd ? x2 : w0; pw.y = odd ? x3 : w1;                                    \
      pw.z = odd ? w2 : x0; pw.w = odd ? w3 : x1;                                    \
      PA = __builtin_bit_cast(bf16x8, pw);                                           \
    }                                                                                \
    {                                                                                \
      u32 w0 = pk2(f0, f1), w1 = pk2(f2, f3), w2 = pk2(f4, f5), w3 = pk2(f6, f7);    \
      u32 x0 = __shfl_xor(w0, 16, 64), x1 = __shfl_xor(w1, 16, 64);                  \
      u32 x2 = __shfl_xor(w2, 16, 64), x3 = __shfl_xor(w3, 16, 64);                  \
      u32x4 pw;                                                                      \
      pw.x = odd ? x2 : w0; pw.y = odd ? x3 : w1;                                    \
      pw.z = odd ? w2 : x0; pw.w = odd ? w3 : x1;                                    \
      PB = __builtin_bit_cast(bf16x8, pw);                                           \
    }                                                                                \
  }

  // ---- prologue: stage tiles 0,1 (12 loads in flight) ----
  STAGE(0, key_base)
  STAGE(1, key_base + 64)

  int cur = 0;  // ring buffer holding tile i
  for (int i = 0; i < NWIN; ++i) {
    if (i < NWIN - 1) {
      asm volatile("s_waitcnt vmcnt(6)" ::: "memory");  // tile i landed; tile i+1 in flight
    } else {
      asm volatile("s_waitcnt vmcnt(0)" ::: "memory");
    }
    __builtin_amdgcn_s_barrier();  // all waves' tile-i DMAs + prior-window reads done
    if (i + 2 < NWIN) {
      int nx = cur + 2; nx = (nx >= 3) ? nx - 3 : nx;
      STAGE(nx, key_base + (i + 2) * 64)
    }

    const u16* kb = kbuf[cur];
    const u16* vb = vbuf[cur];

    // ---- QK^T swapped, 64 keys x 32 q-rows: each K-frag read feeds both q-groups ----
    f32x4 sg0[4], sg1[4];
#pragma unroll
    for (int st = 0; st < 4; ++st) {
      sg0[st] = (f32x4){0.f, 0.f, 0.f, 0.f};
      sg1[st] = (f32x4){0.f, 0.f, 0.f, 0.f};
    }
    __builtin_amdgcn_s_setprio(1);
#pragma unroll
    for (int kf = 0; kf < 4; ++kf) {
      int cs = ((kf * 4 + g) ^ l16) << 3;
#pragma unroll
      for (int st = 0; st < 4; ++st) {
        const u16* kp = kb + (st * 16 + l16) * 128 + cs;
        bf16x8 kh = *(const bf16x8*)(const void*)kp;
        bf16x8 kl = *(const bf16x8*)(const void*)(kp + 8192);
        sg0[st] = MFMA(kh, qh0[kf], sg0[st], 0, 0, 0);
        sg0[st] = MFMA(kh, ql0[kf], sg0[st], 0, 0, 0);
        sg0[st] = MFMA(kl, qh0[kf], sg0[st], 0, 0, 0);
        sg1[st] = MFMA(kh, qh1[kf], sg1[st], 0, 0, 0);
        sg1[st] = MFMA(kh, ql1[kf], sg1[st], 0, 0, 0);
        sg1[st] = MFMA(kl, qh1[kf], sg1[st], 0, 0, 0);
      }
    }
    __builtin_amdgcn_s_setprio(0);

    // ---- softmax + P-pack, one chain per group per 64 keys ----
    bf16x8 pa0A, pa0B, pa1A, pa1B;
    SMPACK(sg0, m0, l0, acc0, pa0A, pa0B)
    SMPACK(sg1, m1, l1, acc1, pa1A, pa1B)

    // ---- PV: one V-frag pair feeds both q-groups ----
    __builtin_amdgcn_s_setprio(1);
#pragma unroll
    for (int nf = 0; nf < 8; ++nf) {
      int d = nf * 16 + l16;
      int sw = (d >> 1) & 7;
      const u16* vr = vb + d * 64;
      bf16x8 vf0 = *(const bf16x8*)(const void*)(vr + ((mg ^ sw) << 3));
      bf16x8 vf1 = *(const bf16x8*)(const void*)(vr + (((4 + mg) ^ sw) << 3));
      acc0[nf] = MFMA(pa0A, vf0, acc0[nf], 0, 0, 0);
      acc0[nf] = MFMA(pa0B, vf1, acc0[nf], 0, 0, 0);
      acc1[nf] = MFMA(pa1A, vf0, acc1[nf], 0, 0, 0);
      acc1[nf] = MFMA(pa1B, vf1, acc1[nf], 0, 0, 0);
    }
    __builtin_amdgcn_s_setprio(0);

    cur = (cur + 1 >= 3) ? cur - 2 : cur + 1;
  }

  // ---- write partials (m, l, O) for the 2 16-row groups ----
  const int pidx0 = sp * NQG + (gr0 >> 4);
  {
    u16* po = PO + (size_t)pidx0 * 16 * DIM;
#pragma unroll
    for (int nf = 0; nf < 8; ++nf)
#pragma unroll
      for (int r = 0; r < 4; ++r)
        po[(g * 4 + r) * DIM + nf * 16 + l16] = f2bu(acc0[nf][r]);
    u16* po1 = PO + (size_t)(pidx0 + 1) * 16 * DIM;
#pragma unroll
    for (int nf = 0; nf < 8; ++nf)
#pragma unroll
      for (int r = 0; r < 4; ++r)
        po1[(g * 4 + r) * DIM + nf * 16 + l16] = f2bu(acc1[nf][r]);
  }
  if (g == 0) { Pm[pidx0 * 16 + l16] = m0; Pl[pidx0 * 16 + l16] = l0; }
  if (g == 1) { Pm[(pidx0 + 1) * 16 + l16] = m1; Pl[(pidx0 + 1) * 16 + l16] = l1; }
#undef STAGE
#undef SMPACK
}

// ---------------- kernel 3: combine KV-split partials (wide loads, 256 thr) ----------------
__global__ __launch_bounds__(256) void k_comb(const float* __restrict__ Pm,
                                              const float* __restrict__ Pl,
                                              const u16* __restrict__ PO,
                                              float* __restrict__ out) {
  const int qg = blockIdx.x;
  const int tid = threadIdx.x;

  __shared__ float sc[NSP][16];  // [split][row]
  if (tid < 16) {
    float m = -1e30f;
#pragma unroll
    for (int s = 0; s < NSP; ++s) m = fmaxf(m, Pm[(s * NQG + qg) * 16 + tid]);
    float den = 0.f;
#pragma unroll
    for (int s = 0; s < NSP; ++s) {
      float e = exp2f(Pm[(s * NQG + qg) * 16 + tid] - m);  // log2-domain stats (cold path)
      sc[s][tid] = e;
      den += Pl[(s * NQG + qg) * 16 + tid] * e;
    }
    float inv = 1.0f / den;
#pragma unroll
    for (int s = 0; s < NSP; ++s) sc[s][tid] *= inv;
  }
  __syncthreads();

  // 2048 elems / 256 thr = 8 per thread (one u16x8 per split, two f32x4 stores)
  const int e0 = tid * 8;
  const int row = e0 >> 7;
  float a[8];
#pragma unroll
  for (int j = 0; j < 8; ++j) a[j] = 0.f;
#pragma unroll
  for (int s = 0; s < NSP; ++s) {
    u16x8 p = *(const u16x8*)(const void*)(PO + (size_t)(s * NQG + qg) * 16 * DIM + e0);
    float wgt = sc[s][row];
#pragma unroll
    for (int j = 0; j < 8; ++j) a[j] += bu2f(p[j]) * wgt;
  }
  float* op = out + (size_t)qg * 16 * DIM + e0;
  f32x4 o0 = {a[0], a[1], a[2], a[3]};
  f32x4 o1 = {a[4], a[5], a[6], a[7]};
  *(f32x4*)op = o0;
  *(f32x4*)(op + 4) = o1;
}

extern "C" void kernel_launch(void* const* d_in, const int* in_sizes, int n_in,
                              void* d_out, int out_size, void* d_ws, size_t ws_size,
                              hipStream_t stream) {
  const float* X  = (const float*)d_in[0];
  const float* wq = (const float*)d_in[4];
  const float* wk = (const float*)d_in[5];
  const float* wv = (const float*)d_in[6];
  float* out = (float*)d_out;

  u16* WT = (u16*)d_ws;                       // 3*2*128*128 u16 = 192 KiB
  u16* Qh = WT + 3 * 2 * 128 * 128;
  u16* Ql = Qh + (size_t)BATCH * S_SRC * DIM; // 2 MiB each
  u16* Kh = Ql + (size_t)BATCH * S_SRC * DIM;
  u16* Kl = Kh + (size_t)BATCH * S_SRC * DIM;
  u16* VT = Kl + (size_t)BATCH * S_SRC * DIM; // [B][D][S]
  float* Pm = (float*)(VT + (size_t)BATCH * S_SRC * DIM);  // [NSP*NQG*16] f32
  float* Pl = Pm + (size_t)NSP * NQG * 16;
  u16* PO = (u16*)(Pl + (size_t)NSP * NQG * 16);           // [NSP*NQG*16*128] bf16 = 16 MiB

  hipLaunchKernelGGL(k_wsplit, dim3(192), dim3(256), 0, stream, wq, wk, wv, WT);
  hipLaunchKernelGGL(k_proj, dim3(BATCH * S_SRC / 32), dim3(256), 0, stream,
                     X, WT, Qh, Ql, Kh, Kl, VT);
  hipLaunchKernelGGL(k_attn, dim3(NQB * NSP), dim3(512), 0, stream,
                     Qh, Ql, Kh, Kl, VT, Pm, Pl, PO);
  hipLaunchKernelGGL(k_comb, dim3(NQG), dim3(256), 0, stream, Pm, Pl, PO, out);
}

// Round 17
// 67.051 us; speedup vs baseline: 2.2945x; 1.0123x over previous
//
#include <hip/hip_runtime.h>
#include <hip/hip_bf16.h>

#define S_SRC 4096
#define DIM 128
#define BATCH 2
#define NSP 8
#define NQB 32    // 256-row q-blocks
#define NQG 512   // 16-row q-groups total
#define NWIN 8    // (S_SRC/NSP)/64 key windows per split

typedef unsigned short u16;
typedef unsigned int u32;
typedef __bf16 bf16x8 __attribute__((ext_vector_type(8)));
typedef float f32x4 __attribute__((ext_vector_type(4)));
typedef u32 u32x4 __attribute__((ext_vector_type(4)));
typedef u16 u16x8 __attribute__((ext_vector_type(8)));

__device__ __forceinline__ __bf16 bf_hi(float x) { return (__bf16)x; }
__device__ __forceinline__ __bf16 bf_lo(float x, __bf16 h) { return (__bf16)(x - (float)h); }
__device__ __forceinline__ u16 bfu(__bf16 h) { return __builtin_bit_cast(u16, h); }
__device__ __forceinline__ u16 f2bu(float x) { return __builtin_bit_cast(u16, (__bf16)x); }
__device__ __forceinline__ float bu2f(u16 u) { return (float)__builtin_bit_cast(__bf16, u); }
__device__ __forceinline__ u32 pk2(float lo, float hi) {
  return (u32)f2bu(lo) | ((u32)f2bu(hi) << 16);
}
// native exp2: v_exp_f32 IS 2^x on AMD — single TRANS instruction, no pre-multiply
__device__ __forceinline__ float ex2(float x) {
  float r;
  asm("v_exp_f32 %0, %1" : "=v"(r) : "v"(x));
  return r;
}
__device__ __forceinline__ void g2l16(const u16* src, u16* ldst) {
  __builtin_amdgcn_global_load_lds((const __attribute__((address_space(1))) void*)src,
                                   (__attribute__((address_space(3))) void*)ldst, 16, 0, 0);
}
#define MFMA __builtin_amdgcn_mfma_f32_16x16x32_bf16

// ---------------- kernel 0: transpose + hi/lo split the weight matrices ----------------
// Wq also folds log2(e)/sqrt(128) so all softmax exponentials run in base-2 (v_exp_f32).
__global__ __launch_bounds__(256) void k_wsplit(const float* __restrict__ wq,
                                                const float* __restrict__ wk,
                                                const float* __restrict__ wv,
                                                u16* __restrict__ wt) {
  int idx = blockIdx.x * 256 + threadIdx.x;  // 3*128*128 = 49152
  int mat = idx >> 14;
  int r = idx & 16383;
  int d = r >> 7, e = r & 127;
  const float* w = (mat == 0) ? wq : ((mat == 1) ? wk : wv);
  float x = w[r];
  if (mat == 0) x *= 0.12751744684693238f;  // log2(e) / sqrt(128)
  __bf16 h = bf_hi(x);
  __bf16 l = bf_lo(x, h);
  wt[((mat * 2 + 0) * 128 + e) * 128 + d] = bfu(h);
  wt[((mat * 2 + 1) * 128 + e) * 128 + d] = bfu(l);
}

// ---------------- kernel 1: QKV projection, col-split for occupancy ----------------
// 512 blocks: each does 32 q-rows x 64 of 128 output cols (2 blocks/CU = 2 waves/SIMD).
__global__ __launch_bounds__(256) void k_proj(const float* __restrict__ X,
                                              const u16* __restrict__ wt,
                                              u16* __restrict__ Qh, u16* __restrict__ Ql,
                                              u16* __restrict__ Kh, u16* __restrict__ Kl,
                                              u16* __restrict__ VT) {
  const int ch = blockIdx.x & 1;          // column half 0/1
  const int t = blockIdx.x >> 1;
  const int b = t >> 7;
  const int tile = t & 127;
  const int tid = threadIdx.x;
  const int w = tid >> 6, lane = tid & 63, g = lane >> 4, l16 = lane & 15;

  bf16x8 a_h[2][4], a_l[2][4];
#pragma unroll
  for (int mf = 0; mf < 2; ++mf) {
    int row = tile * 32 + mf * 16 + l16;
    const float* xr = X + ((size_t)b * S_SRC + row) * DIM;
#pragma unroll
    for (int kf = 0; kf < 4; ++kf) {
      int d0 = kf * 32 + g * 8;
      f32x4 x0 = *(const f32x4*)(xr + d0);
      f32x4 x1 = *(const f32x4*)(xr + d0 + 4);
#pragma unroll
      for (int j = 0; j < 4; ++j) {
        __bf16 h0 = bf_hi(x0[j]);
        __bf16 h1 = bf_hi(x1[j]);
        a_h[mf][kf][j] = h0;
        a_l[mf][kf][j] = bf_lo(x0[j], h0);
        a_h[mf][kf][4 + j] = h1;
        a_l[mf][kf][4 + j] = bf_lo(x1[j], h1);
      }
    }
  }

  const int col = ch * 64 + w * 16 + l16;  // one 16-col fragment per wave
#pragma unroll
  for (int mat = 0; mat < 3; ++mat) {
    const u16* wth = wt + (mat * 2 + 0) * 16384;
    const u16* wtl = wt + (mat * 2 + 1) * 16384;
    f32x4 acc[2];
    acc[0] = (f32x4){0.f, 0.f, 0.f, 0.f};
    acc[1] = (f32x4){0.f, 0.f, 0.f, 0.f};
#pragma unroll
    for (int kf = 0; kf < 4; ++kf) {
      int d0 = kf * 32 + g * 8;
      bf16x8 bh = *(const bf16x8*)(const void*)(wth + col * 128 + d0);
      bf16x8 bl = *(const bf16x8*)(const void*)(wtl + col * 128 + d0);
#pragma unroll
      for (int mf = 0; mf < 2; ++mf) {
        acc[mf] = MFMA(a_h[mf][kf], bh, acc[mf], 0, 0, 0);
        acc[mf] = MFMA(a_h[mf][kf], bl, acc[mf], 0, 0, 0);
        acc[mf] = MFMA(a_l[mf][kf], bh, acc[mf], 0, 0, 0);
      }
    }
#pragma unroll
    for (int mf = 0; mf < 2; ++mf)
#pragma unroll
      for (int r = 0; r < 4; ++r) {
        int row = tile * 32 + mf * 16 + g * 4 + r;
        float v = acc[mf][r];
        if (mat == 2) {
          VT[((size_t)b * DIM + col) * S_SRC + row] = f2bu(v);
        } else {
          __bf16 h = bf_hi(v);
          __bf16 l = bf_lo(v, h);
          size_t o = ((size_t)b * S_SRC + row) * DIM + col;
          if (mat == 0) { Qh[o] = bfu(h); Ql[o] = bfu(l); }
          else          { Kh[o] = bfu(h); Kl[o] = bfu(l); }
        }
      }
  }
}

// ---------------- kernel 2: flash attention, 64-key windows, 3-deep ring ----------------
// Swapped QK^T (A=K, B=Q). Per wave: 2 q-groups of 16 rows. 8 windows of 64 keys.
// Scores are in log2 domain (log2e folded into Wq); all exponentials are v_exp_f32.
__global__ __launch_bounds__(512, 2) void k_attn(const u16* __restrict__ Qh, const u16* __restrict__ Ql,
                                                 const u16* __restrict__ Kh, const u16* __restrict__ Kl,
                                                 const u16* __restrict__ VT,
                                                 float* __restrict__ Pm, float* __restrict__ Pl,
                                                 u16* __restrict__ PO) {
  const int bid = blockIdx.x;
  const int sp = bid & 7;     // kv split 0..7 (== XCD id)
  const int qb = bid >> 3;    // 256-row q-block 0..31
  const int b = qb >> 4;
  const int tid = threadIdx.x;
  const int w = tid >> 6, lane = tid & 63, g = lane >> 4, l16 = lane & 15;

  __shared__ alignas(16) u16 kbuf[3][16384];  // 96KB: [hi 64x128 | lo 64x128] chunk-swizzled
  __shared__ alignas(16) u16 vbuf[3][8192];   // 48KB: [128d x 64s] chunk-swizzled

  // ---- Q fragments (hi/lo), 32 q-rows: 2 groups of 16 ----
  const int gr0 = qb * 256 + w * 32;
  bf16x8 qh0[4], ql0[4], qh1[4], ql1[4];
  {
    const u16* p0h = Qh + ((size_t)gr0 + l16) * DIM;
    const u16* p0l = Ql + ((size_t)gr0 + l16) * DIM;
    const u16* p1h = Qh + ((size_t)gr0 + 16 + l16) * DIM;
    const u16* p1l = Ql + ((size_t)gr0 + 16 + l16) * DIM;
#pragma unroll
    for (int kf = 0; kf < 4; ++kf) {
      int d0 = kf * 32 + g * 8;
      qh0[kf] = *(const bf16x8*)(const void*)(p0h + d0);
      ql0[kf] = *(const bf16x8*)(const void*)(p0l + d0);
      qh1[kf] = *(const bf16x8*)(const void*)(p1h + d0);
      ql1[kf] = *(const bf16x8*)(const void*)(p1l + d0);
    }
  }

  f32x4 acc0[8], acc1[8];
#pragma unroll
  for (int nf = 0; nf < 8; ++nf) {
    acc0[nf] = (f32x4){0.f, 0.f, 0.f, 0.f};
    acc1[nf] = (f32x4){0.f, 0.f, 0.f, 0.f};
  }
  float m0 = -1e30f, m1 = -1e30f, l0 = 0.f, l1 = 0.f;

  const int key_base = sp * (S_SRC / NSP);
  const u16* KhB = Kh + (size_t)b * S_SRC * DIM;
  const u16* KlB = Kl + (size_t)b * S_SRC * DIM;
  const u16* VTB = VT + (size_t)b * DIM * S_SRC;

  // staging (512 threads x 6 chunks of 16B), chunk-XOR swizzle
  const int kkey0 = tid >> 4;                           // key row 0..31 (pass0); +32 pass1
  const int kks = ((tid & 15) ^ (kkey0 & 15)) << 3;     // swizzled source d-offset (elems)
  const int vd0 = tid >> 3;                             // V d-row 0..63 (pass0); +64 pass1
  const int vks = ((tid & 7) ^ ((vd0 >> 1) & 7)) << 3;  // swizzled source s-offset (elems)
  const int wb = w * 512;                               // wave-uniform LDS chunk base (u16)
  const int mg = ((g & 1) << 1) | (g >> 1);             // V key-chunk permutation {0,2,1,3}

#define STAGE(BUF, KEY0)                                                             \
  {                                                                                  \
    g2l16(KhB + ((size_t)((KEY0) + kkey0)) * DIM + kks,      &kbuf[BUF][wb]);        \
    g2l16(KhB + ((size_t)((KEY0) + 32 + kkey0)) * DIM + kks, &kbuf[BUF][4096 + wb]); \
    g2l16(KlB + ((size_t)((KEY0) + kkey0)) * DIM + kks,      &kbuf[BUF][8192 + wb]); \
    g2l16(KlB + ((size_t)((KEY0) + 32 + kkey0)) * DIM + kks, &kbuf[BUF][12288 + wb]);\
    g2l16(VTB + (size_t)vd0 * S_SRC + (KEY0) + vks,          &vbuf[BUF][wb]);        \
    g2l16(VTB + (size_t)(64 + vd0) * S_SRC + (KEY0) + vks,   &vbuf[BUF][4096 + wb]); \
  }

// S = f32x4[4] score array (keys st*16 + g*4 + r of q-col l16), MR/LR running stats,
// ACC = f32x4[8] output acc, PA/PB = packed P A-frags for key-chunks 0/1.
#define SMPACK(S, MR, LR, ACC, PA, PB)                                               \
  {                                                                                  \
    float mxa = fmaxf(fmaxf(fmaxf(S[0][0], S[0][1]), fmaxf(S[0][2], S[0][3])),       \
                      fmaxf(fmaxf(S[1][0], S[1][1]), fmaxf(S[1][2], S[1][3])));      \
    float mxb = fmaxf(fmaxf(fmaxf(S[2][0], S[2][1]), fmaxf(S[2][2], S[2][3])),       \
                      fmaxf(fmaxf(S[3][0], S[3][1]), fmaxf(S[3][2], S[3][3])));      \
    float mx = fmaxf(mxa, mxb);                                                      \
    mx = fmaxf(mx, __shfl_xor(mx, 16, 64));                                          \
    mx = fmaxf(mx, __shfl_xor(mx, 32, 64));                                          \
    if (!__all(mx - MR <= 11.5f)) {                                                  \
      float mn = fmaxf(MR, mx);                                                      \
      float f = ex2(MR - mn);                                                        \
      LR *= f; MR = mn;                                                              \
      float fr0 = __shfl(f, g * 4 + 0, 64);                                          \
      float fr1 = __shfl(f, g * 4 + 1, 64);                                          \
      float fr2 = __shfl(f, g * 4 + 2, 64);                                          \
      float fr3 = __shfl(f, g * 4 + 3, 64);                                          \
      _Pragma("unroll")                                                              \
      for (int nf = 0; nf < 8; ++nf) {                                               \
        ACC[nf][0] *= fr0; ACC[nf][1] *= fr1;                                        \
        ACC[nf][2] *= fr2; ACC[nf][3] *= fr3;                                        \
      }                                                                              \
    }                                                                                \
    float e0 = ex2(S[0][0] - MR), e1 = ex2(S[0][1] - MR);                            \
    float e2 = ex2(S[0][2] - MR), e3 = ex2(S[0][3] - MR);                            \
    float e4 = ex2(S[1][0] - MR), e5 = ex2(S[1][1] - MR);                            \
    float e6 = ex2(S[1][2] - MR), e7 = ex2(S[1][3] - MR);                            \
    float f0 = ex2(S[2][0] - MR), f1 = ex2(S[2][1] - MR);                            \
    float f2 = ex2(S[2][2] - MR), f3 = ex2(S[2][3] - MR);                            \
    float f4 = ex2(S[3][0] - MR), f5 = ex2(S[3][1] - MR);                            \
    float f6 = ex2(S[3][2] - MR), f7 = ex2(S[3][3] - MR);                            \
    float sm = (((e0 + e1) + (e2 + e3)) + ((e4 + e5) + (e6 + e7)))                   \
             + (((f0 + f1) + (f2 + f3)) + ((f4 + f5) + (f6 + f7)));                  \
    sm += __shfl_xor(sm, 16, 64);                                                    \
    sm += __shfl_xor(sm, 32, 64);                                                    \
    LR += sm;                                                                        \
    bool odd = (g & 1);                                                              \
    {                                                                                \
      u32 w0 = pk2(e0, e1), w1 = pk2(e2, e3), w2 = pk2(e4, e5), w3 = pk2(e6, e7);    \
      u32 x0 = __shfl_xor(w0, 16, 64), x1 = __shfl_xor(w1, 16, 64);                  \
      u32 x2 = __shfl_xor(w2, 16, 64), x3 = __shfl_xor(w3, 16, 64);                  \
      u32x4 pw;                                                                      \
      pw.x = odd ? x2 : w0; pw.y = odd ? x3 : w1;                                    \
      pw.z = odd ? w2 : x0; pw.w = odd ? w3 : x1;                                    \
      PA = __builtin_bit_cast(bf16x8, pw);                                           \
    }                                                                                \
    {                                                                                \
      u32 w0 = pk2(f0, f1), w1 = pk2(f2, f3), w2 = pk2(f4, f5), w3 = pk2(f6, f7);    \
      u32 x0 = __shfl_xor(w0, 16, 64), x1 = __shfl_xor(w1, 16, 64);                  \
      u32 x2 = __shfl_xor(w2, 16, 64), x3 = __shfl_xor(w3, 16, 64);                  \
      u32x4 pw;                                                                      \
      pw.x = odd ? x2 : w0; pw.y = odd ? x3 : w1;                                    \
      pw.z = odd ? w2 : x0; pw.w = odd ? w3 : x1;                                    \
      PB = __builtin_bit_cast(bf16x8, pw);                                           \
    }                                                                                \
  }

  // ---- prologue: stage tiles 0,1 (12 loads in flight) ----
  STAGE(0, key_base)
  STAGE(1, key_base + 64)

  int cur = 0;  // ring buffer holding tile i
  for (int i = 0; i < NWIN; ++i) {
    if (i < NWIN - 1) {
      asm volatile("s_waitcnt vmcnt(6)" ::: "memory");  // tile i landed; tile i+1 in flight
    } else {
      asm volatile("s_waitcnt vmcnt(0)" ::: "memory");
    }
    __builtin_amdgcn_s_barrier();  // all waves' tile-i DMAs + prior-window reads done
    if (i + 2 < NWIN) {
      int nx = cur + 2; nx = (nx >= 3) ? nx - 3 : nx;
      STAGE(nx, key_base + (i + 2) * 64)
    }

    const u16* kb = kbuf[cur];
    const u16* vb = vbuf[cur];

    // ---- QK^T swapped, 64 keys x 32 q-rows: each K-frag read feeds both q-groups ----
    f32x4 sg0[4], sg1[4];
#pragma unroll
    for (int st = 0; st < 4; ++st) {
      sg0[st] = (f32x4){0.f, 0.f, 0.f, 0.f};
      sg1[st] = (f32x4){0.f, 0.f, 0.f, 0.f};
    }
    __builtin_amdgcn_s_setprio(1);
#pragma unroll
    for (int kf = 0; kf < 4; ++kf) {
      int cs = ((kf * 4 + g) ^ l16) << 3;
#pragma unroll
      for (int st = 0; st < 4; ++st) {
        const u16* kp = kb + (st * 16 + l16) * 128 + cs;
        bf16x8 kh = *(const bf16x8*)(const void*)kp;
        bf16x8 kl = *(const bf16x8*)(const void*)(kp + 8192);
        sg0[st] = MFMA(kh, qh0[kf], sg0[st], 0, 0, 0);
        sg0[st] = MFMA(kh, ql0[kf], sg0[st], 0, 0, 0);
        sg0[st] = MFMA(kl, qh0[kf], sg0[st], 0, 0, 0);
        sg1[st] = MFMA(kh, qh1[kf], sg1[st], 0, 0, 0);
        sg1[st] = MFMA(kh, ql1[kf], sg1[st], 0, 0, 0);
        sg1[st] = MFMA(kl, qh1[kf], sg1[st], 0, 0, 0);
      }
    }
    __builtin_amdgcn_s_setprio(0);

    // ---- softmax + P-pack, one chain per group per 64 keys ----
    bf16x8 pa0A, pa0B, pa1A, pa1B;
    SMPACK(sg0, m0, l0, acc0, pa0A, pa0B)
    SMPACK(sg1, m1, l1, acc1, pa1A, pa1B)

    // ---- PV: one V-frag pair feeds both q-groups ----
    __builtin_amdgcn_s_setprio(1);
#pragma unroll
    for (int nf = 0; nf < 8; ++nf) {
      int d = nf * 16 + l16;
      int sw = (d >> 1) & 7;
      const u16* vr = vb + d * 64;
      bf16x8 vf0 = *(const bf16x8*)(const void*)(vr + ((mg ^ sw) << 3));
      bf16x8 vf1 = *(const bf16x8*)(const void*)(vr + (((4 + mg) ^ sw) << 3));
      acc0[nf] = MFMA(pa0A, vf0, acc0[nf], 0, 0, 0);
      acc0[nf] = MFMA(pa0B, vf1, acc0[nf], 0, 0, 0);
      acc1[nf] = MFMA(pa1A, vf0, acc1[nf], 0, 0, 0);
      acc1[nf] = MFMA(pa1B, vf1, acc1[nf], 0, 0, 0);
    }
    __builtin_amdgcn_s_setprio(0);

    cur = (cur + 1 >= 3) ? cur - 2 : cur + 1;
  }

  // ---- write partials (m, l, O) for the 2 16-row groups ----
  const int pidx0 = sp * NQG + (gr0 >> 4);
  {
    u16* po = PO + (size_t)pidx0 * 16 * DIM;
#pragma unroll
    for (int nf = 0; nf < 8; ++nf)
#pragma unroll
      for (int r = 0; r < 4; ++r)
        po[(g * 4 + r) * DIM + nf * 16 + l16] = f2bu(acc0[nf][r]);
    u16* po1 = PO + (size_t)(pidx0 + 1) * 16 * DIM;
#pragma unroll
    for (int nf = 0; nf < 8; ++nf)
#pragma unroll
      for (int r = 0; r < 4; ++r)
        po1[(g * 4 + r) * DIM + nf * 16 + l16] = f2bu(acc1[nf][r]);
  }
  if (g == 0) { Pm[pidx0 * 16 + l16] = m0; Pl[pidx0 * 16 + l16] = l0; }
  if (g == 1) { Pm[(pidx0 + 1) * 16 + l16] = m1; Pl[(pidx0 + 1) * 16 + l16] = l1; }
#undef STAGE
#undef SMPACK
}

// ---------------- kernel 3: combine KV-split partials (wide loads, 256 thr) ----------------
__global__ __launch_bounds__(256) void k_comb(const float* __restrict__ Pm,
                                              const float* __restrict__ Pl,
                                              const u16* __restrict__ PO,
                                              float* __restrict__ out) {
  const int qg = blockIdx.x;
  const int tid = threadIdx.x;

  __shared__ float sc[NSP][16];  // [split][row]
  if (tid < 16) {
    float m = -1e30f;
#pragma unroll
    for (int s = 0; s < NSP; ++s) m = fmaxf(m, Pm[(s * NQG + qg) * 16 + tid]);
    float den = 0.f;
#pragma unroll
    for (int s = 0; s < NSP; ++s) {
      float e = exp2f(Pm[(s * NQG + qg) * 16 + tid] - m);  // log2-domain stats (cold path)
      sc[s][tid] = e;
      den += Pl[(s * NQG + qg) * 16 + tid] * e;
    }
    float inv = 1.0f / den;
#pragma unroll
    for (int s = 0; s < NSP; ++s) sc[s][tid] *= inv;
  }
  __syncthreads();

  // 2048 elems / 256 thr = 8 per thread (one u16x8 per split, two f32x4 stores)
  const int e0 = tid * 8;
  const int row = e0 >> 7;
  float a[8];
#pragma unroll
  for (int j = 0; j < 8; ++j) a[j] = 0.f;
#pragma unroll
  for (int s = 0; s < NSP; ++s) {
    u16x8 p = *(const u16x8*)(const void*)(PO + (size_t)(s * NQG + qg) * 16 * DIM + e0);
    float wgt = sc[s][row];
#pragma unroll
    for (int j = 0; j < 8; ++j) a[j] += bu2f(p[j]) * wgt;
  }
  float* op = out + (size_t)qg * 16 * DIM + e0;
  f32x4 o0 = {a[0], a[1], a[2], a[3]};
  f32x4 o1 = {a[4], a[5], a[6], a[7]};
  *(f32x4*)op = o0;
  *(f32x4*)(op + 4) = o1;
}

extern "C" void kernel_launch(void* const* d_in, const int* in_sizes, int n_in,
                              void* d_out, int out_size, void* d_ws, size_t ws_size,
                              hipStream_t stream) {
  const float* X  = (const float*)d_in[0];
  const float* wq = (const float*)d_in[4];
  const float* wk = (const float*)d_in[5];
  const float* wv = (const float*)d_in[6];
  float* out = (float*)d_out;

  u16* WT = (u16*)d_ws;                       // 3*2*128*128 u16 = 192 KiB
  u16* Qh = WT + 3 * 2 * 128 * 128;
  u16* Ql = Qh + (size_t)BATCH * S_SRC * DIM; // 2 MiB each
  u16* Kh = Ql + (size_t)BATCH * S_SRC * DIM;
  u16* Kl = Kh + (size_t)BATCH * S_SRC * DIM;
  u16* VT = Kl + (size_t)BATCH * S_SRC * DIM; // [B][D][S]
  float* Pm = (float*)(VT + (size_t)BATCH * S_SRC * DIM);  // [NSP*NQG*16] f32
  float* Pl = Pm + (size_t)NSP * NQG * 16;
  u16* PO = (u16*)(Pl + (size_t)NSP * NQG * 16);           // [NSP*NQG*16*128] bf16 = 16 MiB

  hipLaunchKernelGGL(k_wsplit, dim3(192), dim3(256), 0, stream, wq, wk, wv, WT);
  hipLaunchKernelGGL(k_proj, dim3(BATCH * S_SRC / 32 * 2), dim3(256), 0, stream,
                     X, WT, Qh, Ql, Kh, Kl, VT);
  hipLaunchKernelGGL(k_attn, dim3(NQB * NSP), dim3(512), 0, stream,
                     Qh, Ql, Kh, Kl, VT, Pm, Pl, PO);
  hipLaunchKernelGGL(k_comb, dim3(NQG), dim3(256), 0, stream, Pm, Pl, PO, out);
}